// Round 9
// baseline (772.608 us; speedup 1.0000x reference)
//
#include <hip/hip_runtime.h>

#define D_MODEL 2048
#define N_HEADS 16
#define D_HEAD 128
#define SEQ 2048
#define BATCH 2
#define M_ROWS (SEQ*BATCH)     // 4096
#define QKV_N  (3*D_MODEL)     // 6144
#define ATTN_SCALE 0.08838834764831845f

typedef __attribute__((ext_vector_type(8))) short short8v;   // 8 bf16 (4 VGPR)
typedef __attribute__((ext_vector_type(4))) float float4v;   // 4 f32 acc
typedef __attribute__((ext_vector_type(2))) unsigned int uint2v;
typedef __attribute__((ext_vector_type(4))) unsigned int uint4v;
typedef unsigned short u16;
typedef unsigned int   u32;

__device__ __forceinline__ u16 f32_bf16_rne(float f) {
    u32 u = __float_as_uint(f);
    return (u16)((u + 0x7FFFu + ((u >> 16) & 1u)) >> 16);
}
__device__ __forceinline__ float bf16_f32(u16 h) {
    return __uint_as_float(((u32)h) << 16);
}

__device__ __forceinline__ void gll16(const void* g, void* l) {
    __builtin_amdgcn_global_load_lds(
        (const __attribute__((address_space(1))) void*)g,
        (__attribute__((address_space(3))) void*)l, 16, 0, 0);
}

// ===========================================================================
// Plane layout for a RxK f32 matrix: hi/lo bf16, tiled [kt][row][32]:
//   off(row, k) = (kt*R + row)*32 + (k & 31),  kt = k >> 5
// ===========================================================================
__global__ __launch_bounds__(256) void split_tiles(
    const float* __restrict__ src, u16* __restrict__ H, u16* __restrict__ L,
    const int R)
{
    const int kt = blockIdx.x, rt = blockIdx.y, t = threadIdx.x;
#pragma unroll
    for (int i = 0; i < 2; ++i) {
        const int s = i*256 + t;
        const int r = s >> 2, sub = s & 3;
        const float* p = src + (size_t)(rt*128 + r)*D_MODEL + kt*32 + sub*8;
        float4 v0 = ((const float4*)p)[0];
        float4 v1 = ((const float4*)p)[1];
        float vv[8] = {v0.x, v0.y, v0.z, v0.w, v1.x, v1.y, v1.z, v1.w};
        u16 hh[8], ll[8];
#pragma unroll
        for (int j = 0; j < 8; ++j) {
            hh[j] = f32_bf16_rne(vv[j]);
            ll[j] = f32_bf16_rne(vv[j] - bf16_f32(hh[j]));
        }
        const size_t off = ((size_t)kt*R + rt*128 + r)*32 + sub*8;
        *(uint4*)&H[off] = *(uint4*)hh;
        *(uint4*)&L[off] = *(uint4*)ll;
    }
}

// ===========================================================================
// bf16x3 GEMM mainloop on pre-split planes (R6-proven single-buffer form:
// 32 KiB LDS, 3 blocks/CU — implicit wave-level overlap beats explicit dbuf).
// ===========================================================================
__device__ __forceinline__ void ps_mainloop(
    const u16* __restrict__ Ah, const u16* __restrict__ Al,
    const u16* __restrict__ Bh, const u16* __restrict__ Bl,
    const int Mrows, const int Nrows, const int m0, const int n0,
    u16* lds, float4v (&acc)[4][4])
{
    const int t = threadIdx.x;
    const int lane = t & 63, wave = t >> 6;
    const int l16 = lane & 15, lg = lane >> 4;
    const int wm = wave >> 1, wn = wave & 1;
    u16* LAh = lds;          u16* LAl = lds + 4096;
    u16* LBh = lds + 8192;   u16* LBl = lds + 12288;
    const int ch0 = wave * 2;

    for (int kt = 0; kt < 64; ++kt) {
        __syncthreads();   // previous iter's frag reads done
        const size_t aoff = ((size_t)kt*Mrows + m0)*32;
        const size_t boff = ((size_t)kt*Nrows + n0)*32;
#pragma unroll
        for (int i = 0; i < 2; ++i) {
            const int ch = ch0 + i;
            const int go = ch*512 + lane*8;
            gll16(Ah + aoff + go, &LAh[ch*512]);
            gll16(Al + aoff + go, &LAl[ch*512]);
            gll16(Bh + boff + go, &LBh[ch*512]);
            gll16(Bl + boff + go, &LBl[ch*512]);
        }
        __syncthreads();   // compiler drains vmcnt(0) before this barrier

        short8v bh[4], bl[4];
#pragma unroll
        for (int fn = 0; fn < 4; ++fn) {
            const int rb = (wn*64 + fn*16 + l16)*32 + lg*8;
            bh[fn] = *(const short8v*)&LBh[rb];
            bl[fn] = *(const short8v*)&LBl[rb];
        }
#pragma unroll
        for (int fm = 0; fm < 4; ++fm) {
            const int ra = (wm*64 + fm*16 + l16)*32 + lg*8;
            short8v ah = *(const short8v*)&LAh[ra];
            short8v al = *(const short8v*)&LAl[ra];
#pragma unroll
            for (int fn = 0; fn < 4; ++fn) {
                acc[fm][fn] = __builtin_amdgcn_mfma_f32_16x16x32_bf16(ah, bh[fn], acc[fm][fn], 0,0,0);
                acc[fm][fn] = __builtin_amdgcn_mfma_f32_16x16x32_bf16(ah, bl[fn], acc[fm][fn], 0,0,0);
                acc[fm][fn] = __builtin_amdgcn_mfma_f32_16x16x32_bf16(al, bh[fn], acc[fm][fn], 0,0,0);
            }
        }
    }
}

__global__ __launch_bounds__(256, 3) void qkv_ps(
    const u16* __restrict__ Xh, const u16* __restrict__ Xl,
    const u16* __restrict__ Wh, const u16* __restrict__ Wl,
    const float* __restrict__ bias, const float* __restrict__ freqs,
    u16* __restrict__ Qh, u16* __restrict__ Ql,
    u16* __restrict__ Kh, u16* __restrict__ Kl,
    u16* __restrict__ Vh, u16* __restrict__ Vl)
{
    __shared__ u16 lds[16384];
    const int m0 = blockIdx.x*128, n0 = blockIdx.y*128;
    float4v acc[4][4];
#pragma unroll
    for (int i = 0; i < 4; ++i)
#pragma unroll
        for (int j = 0; j < 4; ++j)
#pragma unroll
            for (int r = 0; r < 4; ++r) acc[i][j][r] = 0.f;

    ps_mainloop(Xh, Xl, Wh, Wl, M_ROWS, QKV_N, m0, n0, lds, acc);

    const int t = threadIdx.x;
    const int lane = t & 63, wave = t >> 6;
    const int l16 = lane & 15, lg = lane >> 4;
    const int wm = wave >> 1, wn = wave & 1;
    const int sec = n0 >> 11;
    u16* __restrict__ hb = (sec == 0) ? Qh : ((sec == 1) ? Kh : Vh);
    u16* __restrict__ lb = (sec == 0) ? Ql : ((sec == 1) ? Kl : Vl);
#pragma unroll
    for (int fn = 0; fn < 4; ++fn) {
        const int n = n0 + wn*64 + fn*16 + l16;
        const float bn = bias[n];
        const int d = n & 127, hd = (n >> 7) & 15;
#pragma unroll
        for (int fm = 0; fm < 4; ++fm) {
#pragma unroll
            for (int r = 0; r < 4; ++r) {
                const int mrow = m0 + wm*64 + fm*16 + lg*4 + r;
                const int s = mrow >> 1, bb = mrow & 1;
                float v = acc[fm][fn][r] + bn;
                float outv;
                if (sec == 2) {
                    outv = v;
                } else {
                    float partner = __shfl_xor(v, 1, 64);
                    float fr = freqs[(size_t)s * 64 + (d >> 1)];
                    float sn, cs;
                    sincosf(fr, &sn, &cs);
                    outv = (n & 1) ? (partner*sn + v*cs) : (v*cs - partner*sn);
                    if (sec == 0) outv *= ATTN_SCALE;
                }
                size_t off = (((size_t)(bb*N_HEADS + hd) * SEQ) + s) * D_HEAD + d;
                u16 h = f32_bf16_rne(outv);
                hb[off] = h;
                lb[off] = f32_bf16_rne(outv - bf16_f32(h));
            }
        }
    }
}

__global__ __launch_bounds__(256, 3) void out_ps(
    const u16* __restrict__ Aph, const u16* __restrict__ Apl,
    const u16* __restrict__ Wh, const u16* __restrict__ Wl,
    const float* __restrict__ bias, float* __restrict__ Out)
{
    __shared__ u16 lds[16384];
    const int m0 = blockIdx.x*128, n0 = blockIdx.y*128;
    float4v acc[4][4];
#pragma unroll
    for (int i = 0; i < 4; ++i)
#pragma unroll
        for (int j = 0; j < 4; ++j)
#pragma unroll
            for (int r = 0; r < 4; ++r) acc[i][j][r] = 0.f;

    ps_mainloop(Aph, Apl, Wh, Wl, M_ROWS, D_MODEL, m0, n0, lds, acc);

    const int t = threadIdx.x;
    const int lane = t & 63, wave = t >> 6;
    const int l16 = lane & 15, lg = lane >> 4;
    const int wm = wave >> 1, wn = wave & 1;
#pragma unroll
    for (int fn = 0; fn < 4; ++fn) {
        const int n = n0 + wn*64 + fn*16 + l16;
        const float bn = bias[n];
#pragma unroll
        for (int fm = 0; fm < 4; ++fm) {
#pragma unroll
            for (int r = 0; r < 4; ++r) {
                const int mrow = m0 + wm*64 + fm*16 + lg*4 + r;
                Out[(size_t)mrow * D_MODEL + n] = acc[fm][fn][r] + bn;
            }
        }
    }
}

// ===========================================================================
// Attention (bf16x3 MFMA), T14 async K/V prefetch (kept from R8, ~neutral),
// NEW: PV batch-issues all 32 ds_read_b64_tr_b16 with ONE lgkmcnt(0) wait
// (was 8 serial 120-cyc waits -> LDS-latency-serialized at 2 waves/SIMD).
// ===========================================================================
#define QH_O 0
#define QL_O 8192
#define KH_O 16384
#define KL_O 20480
#define VH_O 24576
#define VL_O 28672

__global__ __launch_bounds__(256, 2) void attn_mfma(
    const u16* __restrict__ Qh_g, const u16* __restrict__ Ql_g,
    const u16* __restrict__ Kh_g, const u16* __restrict__ Kl_g,
    const u16* __restrict__ Vh_g, const u16* __restrict__ Vl_g,
    u16* __restrict__ AH, u16* __restrict__ AL)
{
    __shared__ __align__(16) u16 lds[32768];   // 64 KiB

    const int t = threadIdx.x;
    const int lane = t & 63, wave = t >> 6;
    const int l16 = lane & 15, lg = lane >> 4;

    const int bid = blockIdx.x;
    const int bh = (bid & 7) * 4 + ((bid >> 3) >> 4);
    const int pairid = (bid >> 3) & 15;
    const size_t ho = (size_t)bh * SEQ * D_HEAD;

    const int skv = t >> 3;
    const int sdb = t & 7;

    const u32 ldsb = (u32)(uintptr_t)lds;
    const u32 vbH = ldsb + VH_O*2 + lg*256 + l16*8;
    const u32 vbL = ldsb + VL_O*2 + lg*256 + l16*8;

    uint4 kh0, kh1, kl0, kl1, vh0, vh1, vl0, vl1;   // prefetch registers

    auto kvload = [&](int kvb) {
        size_t gk = ho + (size_t)(kvb*32 + skv)*128 + sdb*16;
        kh0 = *(const uint4*)(Kh_g + gk);
        kh1 = *(const uint4*)(Kh_g + gk + 8);
        kl0 = *(const uint4*)(Kl_g + gk);
        kl1 = *(const uint4*)(Kl_g + gk + 8);
        vh0 = *(const uint4*)(Vh_g + gk);
        vh1 = *(const uint4*)(Vh_g + gk + 8);
        vl0 = *(const uint4*)(Vl_g + gk);
        vl1 = *(const uint4*)(Vl_g + gk + 8);
    };
    auto kvwrite = [&]() {
        const int k7 = skv & 7;
        const int g0 = sdb*2, g1 = sdb*2 + 1;
        *(uint4*)&lds[KH_O + skv*128 + ((g0^k7)<<3)] = kh0;
        *(uint4*)&lds[KH_O + skv*128 + ((g1^k7)<<3)] = kh1;
        *(uint4*)&lds[KL_O + skv*128 + ((g0^k7)<<3)] = kl0;
        *(uint4*)&lds[KL_O + skv*128 + ((g1^k7)<<3)] = kl1;
        const int vreg = (sdb*8 + (skv>>2))*64 + (skv&3)*16;
        *(uint4*)&lds[VH_O + vreg]     = vh0;
        *(uint4*)&lds[VH_O + vreg + 8] = vh1;
        *(uint4*)&lds[VL_O + vreg]     = vl0;
        *(uint4*)&lds[VL_O + vreg + 8] = vl1;
    };

    for (int pass = 0; pass < 2; ++pass) {
        const int qb = pass ? (31 - pairid) : pairid;
        const int q0 = qb * 64;
        __syncthreads();   // protect Q region across passes
#pragma unroll
        for (int i = 0; i < 2; ++i) {
            int task = i*256 + t;
            int qr = task >> 3, db = task & 7;
            size_t gsrc = ho + (size_t)(q0 + qr)*128 + db*16;
            uint4 h0 = *(const uint4*)(Qh_g + gsrc);
            uint4 h1 = *(const uint4*)(Qh_g + gsrc + 8);
            uint4 L0 = *(const uint4*)(Ql_g + gsrc);
            uint4 L1 = *(const uint4*)(Ql_g + gsrc + 8);
            *(uint4*)&lds[QH_O + ((db*2  )*64 + qr)*8] = h0;
            *(uint4*)&lds[QH_O + ((db*2+1)*64 + qr)*8] = h1;
            *(uint4*)&lds[QL_O + ((db*2  )*64 + qr)*8] = L0;
            *(uint4*)&lds[QL_O + ((db*2+1)*64 + qr)*8] = L1;
        }
        __syncthreads();
        short8v qfh[4], qfl[4];
#pragma unroll
        for (int c = 0; c < 4; ++c) {
            int g = c*4 + lg;
            qfh[c] = *(const short8v*)&lds[QH_O + (g*64 + wave*16 + l16)*8];
            qfl[c] = *(const short8v*)&lds[QL_O + (g*64 + wave*16 + l16)*8];
        }

        kvload(0);   // prefetch first K/V tile

        float4v o[8];
#pragma unroll
        for (int db = 0; db < 8; ++db)
#pragma unroll
            for (int r = 0; r < 4; ++r) o[db][r] = 0.f;
        float m_s = -1e30f, l_s = 0.f;

        const int jjmax = 2*qb + 1;
        for (int jj = 0; jj <= jjmax; ++jj) {
            const int kv0 = jj * 32;
            __syncthreads();           // prev compute done reading K/V LDS
            kvwrite();                 // ds_writes (wait prefetch via RAW)
            if (jj < jjmax) kvload(jj + 1);   // next tile in flight
            asm volatile("s_waitcnt lgkmcnt(0)" ::: "memory");  // ds_writes done
            __builtin_amdgcn_s_barrier();     // raw: prefetch NOT drained
            __builtin_amdgcn_sched_barrier(0);

            float4v s0 = {0.f,0.f,0.f,0.f}, s1 = {0.f,0.f,0.f,0.f};
#pragma unroll
            for (int c = 0; c < 4; ++c) {
                const int x0 = ((c*4 + lg) ^ (l16 & 7)) << 3;
                short8v K_h0 = *(const short8v*)&lds[KH_O + l16*128 + x0];
                short8v K_l0 = *(const short8v*)&lds[KL_O + l16*128 + x0];
                short8v K_h1 = *(const short8v*)&lds[KH_O + (16+l16)*128 + x0];
                short8v K_l1 = *(const short8v*)&lds[KL_O + (16+l16)*128 + x0];
                s0 = __builtin_amdgcn_mfma_f32_16x16x32_bf16(K_h0, qfh[c], s0, 0,0,0);
                s0 = __builtin_amdgcn_mfma_f32_16x16x32_bf16(K_h0, qfl[c], s0, 0,0,0);
                s0 = __builtin_amdgcn_mfma_f32_16x16x32_bf16(K_l0, qfh[c], s0, 0,0,0);
                s1 = __builtin_amdgcn_mfma_f32_16x16x32_bf16(K_h1, qfh[c], s1, 0,0,0);
                s1 = __builtin_amdgcn_mfma_f32_16x16x32_bf16(K_h1, qfl[c], s1, 0,0,0);
                s1 = __builtin_amdgcn_mfma_f32_16x16x32_bf16(K_l1, qfh[c], s1, 0,0,0);
            }

            const int qg = q0 + wave*16 + l16;
            if (jj >= 2*qb) {
#pragma unroll
                for (int r = 0; r < 4; ++r) {
                    if (kv0 + lg*4 + r > qg)      s0[r] = -1e30f;
                    if (kv0 + 16 + lg*4 + r > qg) s1[r] = -1e30f;
                }
            }

            float mx = fmaxf(fmaxf(fmaxf(s0[0], s0[1]), fmaxf(s0[2], s0[3])),
                             fmaxf(fmaxf(s1[0], s1[1]), fmaxf(s1[2], s1[3])));
            mx = fmaxf(mx, __shfl_xor(mx, 16, 64));
            mx = fmaxf(mx, __shfl_xor(mx, 32, 64));
            const float newm = fmaxf(m_s, mx);
            const float alpha = __expf(m_s - newm);
            m_s = newm;
            float pA[4], pB[4];
#pragma unroll
            for (int r = 0; r < 4; ++r) {
                pA[r] = __expf(s0[r] - newm);
                pB[r] = __expf(s1[r] - newm);
            }
            float rs = (pA[0]+pA[1]+pA[2]+pA[3]) + (pB[0]+pB[1]+pB[2]+pB[3]);
            rs += __shfl_xor(rs, 16, 64);
            rs += __shfl_xor(rs, 32, 64);
            l_s = l_s * alpha + rs;
#pragma unroll
            for (int db = 0; db < 8; ++db)
#pragma unroll
                for (int r = 0; r < 4; ++r) o[db][r] *= alpha;

            u16 ph[8], pl[8];
#pragma unroll
            for (int r = 0; r < 4; ++r) {
                float T1 = __shfl_xor(pA[r], 32, 64);
                float T2 = __shfl_xor(pB[r], 32, 64);
                float pv = (lg==0) ? T1 : (lg==1) ? pA[r] : (lg==2) ? pB[r] : T2;
                float Rv = __shfl_xor(pv, 16, 64);
                float X  = (lg==0) ? pA[r] : (lg==1) ? Rv : (lg==2) ? T2 : Rv;
                float Y  = (lg==0) ? Rv    : (lg==1) ? T1 : (lg==2) ? Rv : pB[r];
                u16 hx = f32_bf16_rne(X);
                ph[r]   = hx; pl[r]   = f32_bf16_rne(X - bf16_f32(hx));
                u16 hy = f32_bf16_rne(Y);
                ph[4+r] = hy; pl[4+r] = f32_bf16_rne(Y - bf16_f32(hy));
            }
            short8v pfh, pfl;
            pfh[0]=(short)ph[0]; pfh[1]=(short)ph[1]; pfh[2]=(short)ph[2]; pfh[3]=(short)ph[3];
            pfh[4]=(short)ph[4]; pfh[5]=(short)ph[5]; pfh[6]=(short)ph[6]; pfh[7]=(short)ph[7];
            pfl[0]=(short)pl[0]; pfl[1]=(short)pl[1]; pfl[2]=(short)pl[2]; pfl[3]=(short)pl[3];
            pfl[4]=(short)pl[4]; pfl[5]=(short)pl[5]; pfl[6]=(short)pl[6]; pfl[7]=(short)pl[7];

            // ---- PV: batch-issue all 32 tr-reads, single wait, 24 MFMAs ----
            uint2v th[8][2], tl[8][2];
#pragma unroll
            for (int DB = 0; DB < 8; ++DB) {
                u32 aH = vbH + DB*1024, aL = vbL + DB*1024;
                asm volatile("ds_read_b64_tr_b16 %0, %4\n\t"
                             "ds_read_b64_tr_b16 %1, %4 offset:128\n\t"
                             "ds_read_b64_tr_b16 %2, %5\n\t"
                             "ds_read_b64_tr_b16 %3, %5 offset:128"
                             : "=v"(th[DB][0]), "=v"(th[DB][1]),
                               "=v"(tl[DB][0]), "=v"(tl[DB][1])
                             : "v"(aH), "v"(aL));
            }
            asm volatile("s_waitcnt lgkmcnt(0)" ::: "memory");
            __builtin_amdgcn_sched_barrier(0);
#pragma unroll
            for (int DB = 0; DB < 8; ++DB) {
                uint4v uh; uh.x = th[DB][0].x; uh.y = th[DB][0].y;
                           uh.z = th[DB][1].x; uh.w = th[DB][1].y;
                uint4v ul; ul.x = tl[DB][0].x; ul.y = tl[DB][0].y;
                           ul.z = tl[DB][1].x; ul.w = tl[DB][1].y;
                short8v vfh = __builtin_bit_cast(short8v, uh);
                short8v vfl = __builtin_bit_cast(short8v, ul);
                o[DB] = __builtin_amdgcn_mfma_f32_16x16x32_bf16(vfh, pfh, o[DB], 0,0,0);
                o[DB] = __builtin_amdgcn_mfma_f32_16x16x32_bf16(vfh, pfl, o[DB], 0,0,0);
                o[DB] = __builtin_amdgcn_mfma_f32_16x16x32_bf16(vfl, pfh, o[DB], 0,0,0);
            }
        }

        // ---- epilogue: tiled hi/lo A-planes for out_ps ----
        const int bb = bh >> 4, hh = bh & 15;
        const float inv = 1.0f / l_s;
        const int s_row = q0 + wave*16 + l16;
        const int m = s_row*BATCH + bb;
#pragma unroll
        for (int tile = 0; tile < 8; ++tile) {
            const int kt = hh*4 + (tile >> 1);
            const size_t off = ((size_t)kt*M_ROWS + m)*32 + (tile & 1)*16 + lg*4;
            u16 hh4[4], ll4[4];
#pragma unroll
            for (int r = 0; r < 4; ++r) {
                float w = o[tile][r]*inv;
                hh4[r] = f32_bf16_rne(w);
                ll4[r] = f32_bf16_rne(w - bf16_f32(hh4[r]));
            }
            *(ushort4*)&AH[off] = make_ushort4(hh4[0], hh4[1], hh4[2], hh4[3]);
            *(ushort4*)&AL[off] = make_ushort4(ll4[0], ll4[1], ll4[2], ll4[3]);
        }
    }
}

extern "C" void kernel_launch(void* const* d_in, const int* in_sizes, int n_in,
                              void* d_out, int out_size, void* d_ws, size_t ws_size,
                              hipStream_t stream) {
    const float* x      = (const float*)d_in[0];
    const float* freqs  = (const float*)d_in[1];
    const float* W_qkv  = (const float*)d_in[2];
    const float* b_qkv  = (const float*)d_in[3];
    const float* W_o    = (const float*)d_in[4];
    const float* b_o    = (const float*)d_in[5];
    float* out = (float*)d_out;

    const size_t PX = (size_t)M_ROWS * D_MODEL;   // 8388608
    const size_t PW = (size_t)QKV_N  * D_MODEL;   // 12582912
    const size_t PO = (size_t)D_MODEL* D_MODEL;   // 4194304
    u16* ws16 = (u16*)d_ws;

    u16* Xh  = ws16;            u16* Xl  = Xh  + PX;
    u16* Wqh = Xl + PX;         u16* Wql = Wqh + PW;
    u16* Woh = Wql + PW;        u16* Wol = Woh + PO;
    u16* Qh  = Wol + PO;        u16* Ql  = Qh + PX;
    u16* Kh  = Ql + PX;         u16* Kl  = Kh + PX;
    u16* Vh  = Kl + PX;         u16* Vl  = Vh + PX;
    u16* Ahp = Vl + PX;         u16* Alp = Ahp + PX;

    split_tiles<<<dim3(64, M_ROWS/128), 256, 0, stream>>>(x,     Xh,  Xl,  M_ROWS);
    split_tiles<<<dim3(64, QKV_N/128),  256, 0, stream>>>(W_qkv, Wqh, Wql, QKV_N);
    split_tiles<<<dim3(64, D_MODEL/128),256, 0, stream>>>(W_o,   Woh, Wol, D_MODEL);
    qkv_ps<<<dim3(M_ROWS/128, QKV_N/128), 256, 0, stream>>>(
        Xh, Xl, Wqh, Wql, b_qkv, freqs, Qh, Ql, Kh, Kl, Vh, Vl);
    attn_mfma<<<dim3(512), 256, 0, stream>>>(Qh, Ql, Kh, Kl, Vh, Vl, Ahp, Alp);
    out_ps<<<dim3(M_ROWS/128, D_MODEL/128), 256, 0, stream>>>(
        Ahp, Alp, Woh, Wol, b_o, out);
}

// Round 10
// 603.295 us; speedup vs baseline: 1.2806x; 1.2806x over previous
//
#include <hip/hip_runtime.h>

#define D_MODEL 2048
#define N_HEADS 16
#define D_HEAD 128
#define SEQ 2048
#define BATCH 2
#define M_ROWS (SEQ*BATCH)     // 4096
#define QKV_N  (3*D_MODEL)     // 6144
#define ATTN_SCALE 0.08838834764831845f

typedef __attribute__((ext_vector_type(8))) short short8v;   // 8 bf16 (4 VGPR)
typedef __attribute__((ext_vector_type(4))) float float4v;   // 4 f32 acc
typedef __attribute__((ext_vector_type(2))) unsigned int uint2v;
typedef __attribute__((ext_vector_type(4))) unsigned int uint4v;
typedef unsigned short u16;
typedef unsigned int   u32;

__device__ __forceinline__ u16 f32_bf16_rne(float f) {
    u32 u = __float_as_uint(f);
    return (u16)((u + 0x7FFFu + ((u >> 16) & 1u)) >> 16);
}
__device__ __forceinline__ float bf16_f32(u16 h) {
    return __uint_as_float(((u32)h) << 16);
}

__device__ __forceinline__ void gll16(const void* g, void* l) {
    __builtin_amdgcn_global_load_lds(
        (const __attribute__((address_space(1))) void*)g,
        (__attribute__((address_space(3))) void*)l, 16, 0, 0);
}

// ===========================================================================
// Plane layout for a RxK f32 matrix, tiled [kt][row][32]:
//   off(row, k) = (kt*R + row)*32 + (k & 31),  kt = k >> 5
// split_tiles: hi+lo planes (weights, B-side). split_tiles_h: hi only (A-side).
// ===========================================================================
__global__ __launch_bounds__(256) void split_tiles(
    const float* __restrict__ src, u16* __restrict__ H, u16* __restrict__ L,
    const int R)
{
    const int kt = blockIdx.x, rt = blockIdx.y, t = threadIdx.x;
#pragma unroll
    for (int i = 0; i < 2; ++i) {
        const int s = i*256 + t;
        const int r = s >> 2, sub = s & 3;
        const float* p = src + (size_t)(rt*128 + r)*D_MODEL + kt*32 + sub*8;
        float4 v0 = ((const float4*)p)[0];
        float4 v1 = ((const float4*)p)[1];
        float vv[8] = {v0.x, v0.y, v0.z, v0.w, v1.x, v1.y, v1.z, v1.w};
        u16 hh[8], ll[8];
#pragma unroll
        for (int j = 0; j < 8; ++j) {
            hh[j] = f32_bf16_rne(vv[j]);
            ll[j] = f32_bf16_rne(vv[j] - bf16_f32(hh[j]));
        }
        const size_t off = ((size_t)kt*R + rt*128 + r)*32 + sub*8;
        *(uint4*)&H[off] = *(uint4*)hh;
        *(uint4*)&L[off] = *(uint4*)ll;
    }
}

__global__ __launch_bounds__(256) void split_tiles_h(
    const float* __restrict__ src, u16* __restrict__ H, const int R)
{
    const int kt = blockIdx.x, rt = blockIdx.y, t = threadIdx.x;
#pragma unroll
    for (int i = 0; i < 2; ++i) {
        const int s = i*256 + t;
        const int r = s >> 2, sub = s & 3;
        const float* p = src + (size_t)(rt*128 + r)*D_MODEL + kt*32 + sub*8;
        float4 v0 = ((const float4*)p)[0];
        float4 v1 = ((const float4*)p)[1];
        float vv[8] = {v0.x, v0.y, v0.z, v0.w, v1.x, v1.y, v1.z, v1.w};
        u16 hh[8];
#pragma unroll
        for (int j = 0; j < 8; ++j) hh[j] = f32_bf16_rne(vv[j]);
        const size_t off = ((size_t)kt*R + rt*128 + r)*32 + sub*8;
        *(uint4*)&H[off] = *(uint4*)hh;
    }
}

// ===========================================================================
// x2-asymmetric GEMM mainloop: C ~= Ah*(Bh + Bl).  A bf16-rounded (error
// 2^-9 rel), B split-exact. 32 MFMA / 24 KB LDS per K-tile (was 48 / 32KB).
// Single-buffer R6-proven form; 4 blocks/CU.
// ===========================================================================
__device__ __forceinline__ void ps_mainloop(
    const u16* __restrict__ Ah,
    const u16* __restrict__ Bh, const u16* __restrict__ Bl,
    const int Mrows, const int Nrows, const int m0, const int n0,
    u16* lds, float4v (&acc)[4][4])
{
    const int t = threadIdx.x;
    const int lane = t & 63, wave = t >> 6;
    const int l16 = lane & 15, lg = lane >> 4;
    const int wm = wave >> 1, wn = wave & 1;
    u16* LAh = lds;          // 4096 u16
    u16* LBh = lds + 4096;
    u16* LBl = lds + 8192;
    const int ch0 = wave * 2;

    for (int kt = 0; kt < 64; ++kt) {
        __syncthreads();   // previous iter's frag reads done
        const size_t aoff = ((size_t)kt*Mrows + m0)*32;
        const size_t boff = ((size_t)kt*Nrows + n0)*32;
#pragma unroll
        for (int i = 0; i < 2; ++i) {
            const int ch = ch0 + i;
            const int go = ch*512 + lane*8;
            gll16(Ah + aoff + go, &LAh[ch*512]);
            gll16(Bh + boff + go, &LBh[ch*512]);
            gll16(Bl + boff + go, &LBl[ch*512]);
        }
        __syncthreads();   // compiler drains vmcnt(0) before this barrier

        short8v bh[4], bl[4];
#pragma unroll
        for (int fn = 0; fn < 4; ++fn) {
            const int rb = (wn*64 + fn*16 + l16)*32 + lg*8;
            bh[fn] = *(const short8v*)&LBh[rb];
            bl[fn] = *(const short8v*)&LBl[rb];
        }
#pragma unroll
        for (int fm = 0; fm < 4; ++fm) {
            const int ra = (wm*64 + fm*16 + l16)*32 + lg*8;
            short8v ah = *(const short8v*)&LAh[ra];
#pragma unroll
            for (int fn = 0; fn < 4; ++fn) {
                acc[fm][fn] = __builtin_amdgcn_mfma_f32_16x16x32_bf16(ah, bh[fn], acc[fm][fn], 0,0,0);
                acc[fm][fn] = __builtin_amdgcn_mfma_f32_16x16x32_bf16(ah, bl[fn], acc[fm][fn], 0,0,0);
            }
        }
    }
}

// Kernel 1: QKV projection + bias + RoPE; Q -> hi/lo planes, K/V -> hi only.
__global__ __launch_bounds__(256, 4) void qkv_ps(
    const u16* __restrict__ Xh,
    const u16* __restrict__ Wh, const u16* __restrict__ Wl,
    const float* __restrict__ bias, const float* __restrict__ freqs,
    u16* __restrict__ Qh, u16* __restrict__ Ql,
    u16* __restrict__ Kh, u16* __restrict__ Vh)
{
    __shared__ u16 lds[12288];   // 24 KiB
    const int m0 = blockIdx.x*128, n0 = blockIdx.y*128;
    float4v acc[4][4];
#pragma unroll
    for (int i = 0; i < 4; ++i)
#pragma unroll
        for (int j = 0; j < 4; ++j)
#pragma unroll
            for (int r = 0; r < 4; ++r) acc[i][j][r] = 0.f;

    ps_mainloop(Xh, Wh, Wl, M_ROWS, QKV_N, m0, n0, lds, acc);

    const int t = threadIdx.x;
    const int lane = t & 63, wave = t >> 6;
    const int l16 = lane & 15, lg = lane >> 4;
    const int wm = wave >> 1, wn = wave & 1;
    const int sec = n0 >> 11;
    u16* __restrict__ hb = (sec == 0) ? Qh : ((sec == 1) ? Kh : Vh);
#pragma unroll
    for (int fn = 0; fn < 4; ++fn) {
        const int n = n0 + wn*64 + fn*16 + l16;
        const float bn = bias[n];
        const int d = n & 127, hd = (n >> 7) & 15;
#pragma unroll
        for (int fm = 0; fm < 4; ++fm) {
#pragma unroll
            for (int r = 0; r < 4; ++r) {
                const int mrow = m0 + wm*64 + fm*16 + lg*4 + r;
                const int s = mrow >> 1, bb = mrow & 1;
                float v = acc[fm][fn][r] + bn;
                float outv;
                if (sec == 2) {
                    outv = v;
                } else {
                    float partner = __shfl_xor(v, 1, 64);
                    float fr = freqs[(size_t)s * 64 + (d >> 1)];
                    float sn, cs;
                    sincosf(fr, &sn, &cs);
                    outv = (n & 1) ? (partner*sn + v*cs) : (v*cs - partner*sn);
                    if (sec == 0) outv *= ATTN_SCALE;
                }
                size_t off = (((size_t)(bb*N_HEADS + hd) * SEQ) + s) * D_HEAD + d;
                u16 h = f32_bf16_rne(outv);
                hb[off] = h;
                if (sec == 0) Ql[off] = f32_bf16_rne(outv - bf16_f32(h));
            }
        }
    }
}

// Kernel 3: output projection, A = attn hi plane only, W hi/lo.
__global__ __launch_bounds__(256, 4) void out_ps(
    const u16* __restrict__ Aph,
    const u16* __restrict__ Wh, const u16* __restrict__ Wl,
    const float* __restrict__ bias, float* __restrict__ Out)
{
    __shared__ u16 lds[12288];
    const int m0 = blockIdx.x*128, n0 = blockIdx.y*128;
    float4v acc[4][4];
#pragma unroll
    for (int i = 0; i < 4; ++i)
#pragma unroll
        for (int j = 0; j < 4; ++j)
#pragma unroll
            for (int r = 0; r < 4; ++r) acc[i][j][r] = 0.f;

    ps_mainloop(Aph, Wh, Wl, M_ROWS, D_MODEL, m0, n0, lds, acc);

    const int t = threadIdx.x;
    const int lane = t & 63, wave = t >> 6;
    const int l16 = lane & 15, lg = lane >> 4;
    const int wm = wave >> 1, wn = wave & 1;
#pragma unroll
    for (int fn = 0; fn < 4; ++fn) {
        const int n = n0 + wn*64 + fn*16 + l16;
        const float bn = bias[n];
#pragma unroll
        for (int fm = 0; fm < 4; ++fm) {
#pragma unroll
            for (int r = 0; r < 4; ++r) {
                const int mrow = m0 + wm*64 + fm*16 + lg*4 + r;
                Out[(size_t)mrow * D_MODEL + n] = acc[fm][fn][r] + bn;
            }
        }
    }
}

// ===========================================================================
// Attention, x2-asymmetric (R6-proven structure, serial in-loop K/V staging,
// per-DB PV waits). Scores ~= Kh*(Qh+Ql); PV ~= Vh*(Ph+Pl).
// LDS 48 KiB: QH 16K | QL 16K | KH 8K (swizzled) | VH 8K (tr-read regions).
// ===========================================================================
#define QH_O 0
#define QL_O 8192
#define KH_O 16384
#define VH_O 20480

__global__ __launch_bounds__(256, 2) void attn_mfma(
    const u16* __restrict__ Qh_g, const u16* __restrict__ Ql_g,
    const u16* __restrict__ Kh_g, const u16* __restrict__ Vh_g,
    u16* __restrict__ AH)
{
    __shared__ __align__(16) u16 lds[24576];   // 48 KiB

    const int t = threadIdx.x;
    const int lane = t & 63, wave = t >> 6;
    const int l16 = lane & 15, lg = lane >> 4;

    const int bid = blockIdx.x;
    const int bh = (bid & 7) * 4 + ((bid >> 3) >> 4);   // XCD-aware
    const int pairid = (bid >> 3) & 15;
    const size_t ho = (size_t)bh * SEQ * D_HEAD;

    const int skv = t >> 3;        // staging K/V row 0..31
    const int sdb = t & 7;         // staging d-block

    const u32 ldsb = (u32)(uintptr_t)lds;
    const u32 vbH = ldsb + VH_O*2 + lg*256 + l16*8;

    for (int pass = 0; pass < 2; ++pass) {
        const int qb = pass ? (31 - pairid) : pairid;
        const int q0 = qb * 64;
        __syncthreads();   // protect Q region across passes
        // ---- stage Q tile (hi+lo), k-major [g][q][8] ----
#pragma unroll
        for (int i = 0; i < 2; ++i) {
            int task = i*256 + t;
            int qr = task >> 3, db = task & 7;
            size_t gsrc = ho + (size_t)(q0 + qr)*128 + db*16;
            uint4 h0 = *(const uint4*)(Qh_g + gsrc);
            uint4 h1 = *(const uint4*)(Qh_g + gsrc + 8);
            uint4 L0 = *(const uint4*)(Ql_g + gsrc);
            uint4 L1 = *(const uint4*)(Ql_g + gsrc + 8);
            *(uint4*)&lds[QH_O + ((db*2  )*64 + qr)*8] = h0;
            *(uint4*)&lds[QH_O + ((db*2+1)*64 + qr)*8] = h1;
            *(uint4*)&lds[QL_O + ((db*2  )*64 + qr)*8] = L0;
            *(uint4*)&lds[QL_O + ((db*2+1)*64 + qr)*8] = L1;
        }
        __syncthreads();
        // ---- Q fragments to registers (persist across KV loop) ----
        short8v qfh[4], qfl[4];
#pragma unroll
        for (int c = 0; c < 4; ++c) {
            int g = c*4 + lg;
            qfh[c] = *(const short8v*)&lds[QH_O + (g*64 + wave*16 + l16)*8];
            qfl[c] = *(const short8v*)&lds[QL_O + (g*64 + wave*16 + l16)*8];
        }

        float4v o[8];
#pragma unroll
        for (int db = 0; db < 8; ++db)
#pragma unroll
            for (int r = 0; r < 4; ++r) o[db][r] = 0.f;
        float m_s = -1e30f, l_s = 0.f;

        const int jjmax = 2*qb + 1;
        for (int jj = 0; jj <= jjmax; ++jj) {
            const int kv0 = jj * 32;
            __syncthreads();
            // ---- stage K (swizzled k-major) and V (tr-read regions), hi only ----
            {
                size_t gk = ho + (size_t)(kv0 + skv)*128 + sdb*16;
                uint4 kh0 = *(const uint4*)(Kh_g + gk);
                uint4 kh1 = *(const uint4*)(Kh_g + gk + 8);
                uint4 vh0 = *(const uint4*)(Vh_g + gk);
                uint4 vh1 = *(const uint4*)(Vh_g + gk + 8);
                const int k7 = skv & 7;
                const int g0 = sdb*2, g1 = sdb*2 + 1;
                *(uint4*)&lds[KH_O + skv*128 + ((g0^k7)<<3)] = kh0;
                *(uint4*)&lds[KH_O + skv*128 + ((g1^k7)<<3)] = kh1;
                const int vreg = (sdb*8 + (skv>>2))*64 + (skv&3)*16;
                *(uint4*)&lds[VH_O + vreg]     = vh0;
                *(uint4*)&lds[VH_O + vreg + 8] = vh1;
            }
            __syncthreads();

            // ---- scores S^T: rows kv = lg*4+r (+16), cols q = l16 ----
            float4v s0 = {0.f,0.f,0.f,0.f}, s1 = {0.f,0.f,0.f,0.f};
#pragma unroll
            for (int c = 0; c < 4; ++c) {
                const int x0 = ((c*4 + lg) ^ (l16 & 7)) << 3;
                short8v K_h0 = *(const short8v*)&lds[KH_O + l16*128 + x0];
                short8v K_h1 = *(const short8v*)&lds[KH_O + (16+l16)*128 + x0];
                s0 = __builtin_amdgcn_mfma_f32_16x16x32_bf16(K_h0, qfh[c], s0, 0,0,0);
                s0 = __builtin_amdgcn_mfma_f32_16x16x32_bf16(K_h0, qfl[c], s0, 0,0,0);
                s1 = __builtin_amdgcn_mfma_f32_16x16x32_bf16(K_h1, qfh[c], s1, 0,0,0);
                s1 = __builtin_amdgcn_mfma_f32_16x16x32_bf16(K_h1, qfl[c], s1, 0,0,0);
            }

            // ---- causal mask (last two tiles only) ----
            const int qg = q0 + wave*16 + l16;
            if (jj >= 2*qb) {
#pragma unroll
                for (int r = 0; r < 4; ++r) {
                    if (kv0 + lg*4 + r > qg)      s0[r] = -1e30f;
                    if (kv0 + 16 + lg*4 + r > qg) s1[r] = -1e30f;
                }
            }

            // ---- online softmax (q per-lane; reduce over lg via shfl) ----
            float mx = fmaxf(fmaxf(fmaxf(s0[0], s0[1]), fmaxf(s0[2], s0[3])),
                             fmaxf(fmaxf(s1[0], s1[1]), fmaxf(s1[2], s1[3])));
            mx = fmaxf(mx, __shfl_xor(mx, 16, 64));
            mx = fmaxf(mx, __shfl_xor(mx, 32, 64));
            const float newm = fmaxf(m_s, mx);
            const float alpha = __expf(m_s - newm);
            m_s = newm;
            float pA[4], pB[4];
#pragma unroll
            for (int r = 0; r < 4; ++r) {
                pA[r] = __expf(s0[r] - newm);
                pB[r] = __expf(s1[r] - newm);
            }
            float rs = (pA[0]+pA[1]+pA[2]+pA[3]) + (pB[0]+pB[1]+pB[2]+pB[3]);
            rs += __shfl_xor(rs, 16, 64);
            rs += __shfl_xor(rs, 32, 64);
            l_s = l_s * alpha + rs;
#pragma unroll
            for (int db = 0; db < 8; ++db)
#pragma unroll
                for (int r = 0; r < 4; ++r) o[db][r] *= alpha;

            // ---- redistribute P quads to B-frag kv layout, split to bf16 ----
            u16 ph[8], pl[8];
#pragma unroll
            for (int r = 0; r < 4; ++r) {
                float T1 = __shfl_xor(pA[r], 32, 64);
                float T2 = __shfl_xor(pB[r], 32, 64);
                float pv = (lg==0) ? T1 : (lg==1) ? pA[r] : (lg==2) ? pB[r] : T2;
                float Rv = __shfl_xor(pv, 16, 64);
                float X  = (lg==0) ? pA[r] : (lg==1) ? Rv : (lg==2) ? T2 : Rv;
                float Y  = (lg==0) ? Rv    : (lg==1) ? T1 : (lg==2) ? Rv : pB[r];
                u16 hx = f32_bf16_rne(X);
                ph[r]   = hx; pl[r]   = f32_bf16_rne(X - bf16_f32(hx));
                u16 hy = f32_bf16_rne(Y);
                ph[4+r] = hy; pl[4+r] = f32_bf16_rne(Y - bf16_f32(hy));
            }
            short8v pfh, pfl;
            pfh[0]=(short)ph[0]; pfh[1]=(short)ph[1]; pfh[2]=(short)ph[2]; pfh[3]=(short)ph[3];
            pfh[4]=(short)ph[4]; pfh[5]=(short)ph[5]; pfh[6]=(short)ph[6]; pfh[7]=(short)ph[7];
            pfl[0]=(short)pl[0]; pfl[1]=(short)pl[1]; pfl[2]=(short)pl[2]; pfl[3]=(short)pl[3];
            pfl[4]=(short)pl[4]; pfl[5]=(short)pl[5]; pfl[6]=(short)pl[6]; pfl[7]=(short)pl[7];

            // ---- PV via hardware transpose reads: O^T[d][q] (hi V only) ----
#pragma unroll
            for (int DB = 0; DB < 8; ++DB) {
                uint2v th0, th1;
                u32 aH = vbH + DB*1024;
                asm volatile("ds_read_b64_tr_b16 %0, %2\n\t"
                             "ds_read_b64_tr_b16 %1, %2 offset:128\n\t"
                             "s_waitcnt lgkmcnt(0)"
                             : "=v"(th0), "=v"(th1)
                             : "v"(aH));
                __builtin_amdgcn_sched_barrier(0);
                uint4v uh; uh.x = th0.x; uh.y = th0.y; uh.z = th1.x; uh.w = th1.y;
                short8v vfh = __builtin_bit_cast(short8v, uh);
                o[DB] = __builtin_amdgcn_mfma_f32_16x16x32_bf16(vfh, pfh, o[DB], 0,0,0);
                o[DB] = __builtin_amdgcn_mfma_f32_16x16x32_bf16(vfh, pfl, o[DB], 0,0,0);
            }
        }

        // ---- epilogue: tiled hi A-plane for out_ps ----
        const int bb = bh >> 4, hh = bh & 15;
        const float inv = 1.0f / l_s;
        const int s_row = q0 + wave*16 + l16;
        const int m = s_row*BATCH + bb;
#pragma unroll
        for (int tile = 0; tile < 8; ++tile) {
            const int kt = hh*4 + (tile >> 1);
            const size_t off = ((size_t)kt*M_ROWS + m)*32 + (tile & 1)*16 + lg*4;
            u16 hh4[4];
#pragma unroll
            for (int r = 0; r < 4; ++r) hh4[r] = f32_bf16_rne(o[tile][r]*inv);
            *(ushort4*)&AH[off] = make_ushort4(hh4[0], hh4[1], hh4[2], hh4[3]);
        }
    }
}

extern "C" void kernel_launch(void* const* d_in, const int* in_sizes, int n_in,
                              void* d_out, int out_size, void* d_ws, size_t ws_size,
                              hipStream_t stream) {
    const float* x      = (const float*)d_in[0];
    const float* freqs  = (const float*)d_in[1];
    const float* W_qkv  = (const float*)d_in[2];
    const float* b_qkv  = (const float*)d_in[3];
    const float* W_o    = (const float*)d_in[4];
    const float* b_o    = (const float*)d_in[5];
    float* out = (float*)d_out;

    const size_t PX = (size_t)M_ROWS * D_MODEL;   // 8388608
    const size_t PW = (size_t)QKV_N  * D_MODEL;   // 12582912
    const size_t PO = (size_t)D_MODEL* D_MODEL;   // 4194304
    u16* ws16 = (u16*)d_ws;

    u16* Xh  = ws16;            // PX
    u16* Wqh = Xh  + PX;        u16* Wql = Wqh + PW;
    u16* Woh = Wql + PW;        u16* Wol = Woh + PO;
    u16* Qh  = Wol + PO;        u16* Ql  = Qh + PX;
    u16* Kh  = Ql + PX;         u16* Vh  = Kh + PX;
    u16* AHp = Vh + PX;         // PX   -> total 160 MiB

    split_tiles_h<<<dim3(64, M_ROWS/128), 256, 0, stream>>>(x, Xh, M_ROWS);
    split_tiles<<<dim3(64, QKV_N/128),  256, 0, stream>>>(W_qkv, Wqh, Wql, QKV_N);
    split_tiles<<<dim3(64, D_MODEL/128),256, 0, stream>>>(W_o,   Woh, Wol, D_MODEL);
    qkv_ps<<<dim3(M_ROWS/128, QKV_N/128), 256, 0, stream>>>(
        Xh, Wqh, Wql, b_qkv, freqs, Qh, Ql, Kh, Vh);
    attn_mfma<<<dim3(512), 256, 0, stream>>>(Qh, Ql, Kh, Vh, AHp);
    out_ps<<<dim3(M_ROWS/128, D_MODEL/128), 256, 0, stream>>>(
        AHp, Woh, Wol, b_o, out);
}